// Round 7
// baseline (7451.920 us; speedup 1.0000x reference)
//
#include <hip/hip_runtime.h>
#include <stdint.h>

// Encoder: 2-layer bidirectional masked LSTM. B=32 T=1024 D=H=512 G=4H=2048.
// v6 = v5 compute core + v4-proven comm protocol.
//  - 32x32x16 MFMA; Wk AND Wr register-resident (8+8 f16x8 = 64 VGPR/lane).
//  - conflict-free zbuf[2][4][32][48]; LDS pad forces 1 WG/CU.
//  - h exchange: plain stores/loads through the direction's shared XCD L2
//    (claim protocol pins all 32 WGs of a dir to one XCD; v3/v4-proven).
//  - step flags: agent-scope atomics via MALL (v2/v3/v4-proven; the v5b
//    hand-rolled sc0 poll hung — reverted).

#define B_ 32
#define T_ 1024
#define H_ 512
#define G_ 2048

typedef _Float16 f16;
typedef _Float16 f16x8 __attribute__((ext_vector_type(8)));
typedef float f32x16 __attribute__((ext_vector_type(16)));

#define AL_U(p) __hip_atomic_load((p), __ATOMIC_RELAXED, __HIP_MEMORY_SCOPE_AGENT)
#define AS_U(p, v) __hip_atomic_store((p), (v), __ATOMIC_RELAXED, __HIP_MEMORY_SCOPE_AGENT)
#define AADD_U(p, v) __hip_atomic_fetch_add((p), (v), __ATOMIC_RELAXED, __HIP_MEMORY_SCOPE_AGENT)

struct Claim {
  unsigned cnt[8];
  unsigned dirclaim;
  int xcddir[8];   // 0=undecided, 1/2=dir+1, -1=unused XCD
  unsigned pad[15];
};

__device__ __forceinline__ float sigm(float x) { return 1.f / (1.f + __expf(-x)); }
__device__ __forceinline__ float tanh_(float x) { return 1.f - 2.f / (__expf(2.f * x) + 1.f); }

// ---------------------------------------------------------------- converts
// x [b][t][512] f32 -> xh [t][ks32][b32][kk16] f16 (MFMA-A fragment-native)
__global__ void cvt_x_t(const float* __restrict__ x, f16* __restrict__ xh) {
  size_t j = (size_t)blockIdx.x * 256 + threadIdx.x;  // 2,097,152 threads
  int b = (int)(j >> 16);
  int t = (int)((j >> 6) & 1023);
  int d0 = (int)(j & 63) * 8;
  const float4* p = (const float4*)(x + ((size_t)b * T_ + t) * H_ + d0);
  float4 a = p[0], c = p[1];
  union { f16 h[8]; uint4 u; } r;
  r.h[0] = (f16)a.x; r.h[1] = (f16)a.y; r.h[2] = (f16)a.z; r.h[3] = (f16)a.w;
  r.h[4] = (f16)c.x; r.h[5] = (f16)c.y; r.h[6] = (f16)c.z; r.h[7] = (f16)c.w;
  size_t o = (((size_t)t * 32 + (d0 >> 4)) * 32 + b) * 16 + (d0 & 15);
  *(uint4*)(xh + o) = r.u;
}

// W [z4][k512][g2048] f32 -> wb [z4][wgi32][cp2][ks32][col32][kk16] f16
// where gate col = (2*cp + (col>>4))*512 + wgi*16 + (col&15), k = ks*16+kk.
__global__ void cvt_w(const float* __restrict__ W, f16* __restrict__ Wb) {
  const int wgi = blockIdx.x, z = blockIdx.y;
  const int tid = threadIdx.x;
  const float* src = W + (size_t)z * H_ * G_;
  __shared__ unsigned short st[512];
  for (int cp = 0; cp < 2; ++cp)
    for (int ks = 0; ks < 32; ++ks) {
      size_t cbase = ((((size_t)z * 32 + wgi) * 2 + cp) * 32 + ks) * 512;
#pragma unroll
      for (int pass = 0; pass < 2; ++pass) {
        int e = tid + pass * 256;
        int col = e & 31, kk = e >> 5;
        int gc = (2 * cp + (col >> 4)) * 512 + wgi * 16 + (col & 15);
        f16 v = (f16)src[(size_t)(ks * 16 + kk) * G_ + gc];
        st[col * 16 + kk] = __builtin_bit_cast(unsigned short, v);
      }
      __syncthreads();
      unsigned pk = (unsigned)st[2 * tid] | ((unsigned)st[2 * tid + 1] << 16);
      *((unsigned*)(Wb + cbase) + tid) = pk;
      __syncthreads();
    }
}

// res1h = hf + hb (elementwise; layouts identical)
__global__ void sum_h(const f16* __restrict__ a, const f16* __restrict__ b,
                      f16* __restrict__ r) {
  size_t i = ((size_t)blockIdx.x * 256 + threadIdx.x) * 8;
  f16x8 va = *(const f16x8*)(a + i), vb = *(const f16x8*)(b + i);
  *(f16x8*)(r + i) = va + vb;
}

// ---------------------------------------------------------------- recurrence
// Role WG: 512 thr, 8 waves: cp=wave&1 (coltile: gates i,f | g,o), kq=wave>>1
// (K-chunk of 128). All weights VGPR-resident (8+8 f16x8 frags = 64 VGPR).
// LAYER0: ring = d_out scratch [dir][t][16384] (doubles as hf/hb output).
// LAYER1: ring = 8-slot; out[b][t][512] += h (+res1 for dir0) after signal.
template <int LAYER>
__global__ __launch_bounds__(512, 2) void lstm_rec6(
    const f16* __restrict__ xh,     // [t][ks][b][kk]
    const f16* __restrict__ wkb,    // [z][wgi][cp][ks][col][kk]
    const f16* __restrict__ wrb,
    const float* __restrict__ biasAll,  // [2][2][2048]
    const void* __restrict__ maskp,
    f16* __restrict__ ring,
    unsigned* __restrict__ flags,   // [2][1024][32] u32, pre-zeroed
    Claim* __restrict__ cl,         // pre-zeroed
    float* __restrict__ out,        // LAYER1 only
    const f16* __restrict__ res1h)  // LAYER1 only
{
  const int tid = threadIdx.x, wave = tid >> 6, lane = tid & 63;

  // ---- role claim (tid 0), broadcast via LDS (v3/v4-proven)
  __shared__ int s_dir, s_wgi;
  __shared__ float zbuf[2][4][32][48];   // 49,152 B, conflict-free strides
  __shared__ char lds_pad[33024];        // force 1 WG/CU (total > 80 KiB)

  if (tid == 0) {
    unsigned xcd;
    asm volatile("s_getreg_b32 %0, hwreg(HW_REG_XCC_ID)" : "=s"(xcd));
    xcd &= 7u;
    unsigned slot = AADD_U(&cl->cnt[xcd], 1u);
    int dir = -1, wgi = -1;
    if (slot < 32u) {
      if (slot == 31u) {
        unsigned d = AADD_U(&cl->dirclaim, 1u);
        int val = (d < 2u) ? (int)(d + 1u) : -1;
        __hip_atomic_store(&cl->xcddir[xcd], val, __ATOMIC_RELAXED, __HIP_MEMORY_SCOPE_AGENT);
      }
      while (true) {
        int v = __hip_atomic_load(&cl->xcddir[xcd], __ATOMIC_RELAXED, __HIP_MEMORY_SCOPE_AGENT);
        if (v != 0) { if (v > 0) { dir = v - 1; wgi = (int)slot; } break; }
        if (AL_U(&cl->dirclaim) >= 2u && AL_U(&cl->cnt[xcd]) < 32u) break;
        __builtin_amdgcn_s_sleep(2);
      }
    }
    s_dir = dir; s_wgi = wgi;
  }
  __syncthreads();
  const int dir = s_dir, wgi = s_wgi;
  if (dir < 0) return;
  if (s_dir == -2) ((volatile char*)lds_pad)[tid] = 1;  // keep pad allocated

  const int cp = wave & 1, kq = wave >> 1;
  const int j0 = wgi * 16;
  const int z = LAYER * 2 + dir;
  const int laneA = (lane & 31) * 16 + (lane >> 5) * 8;  // A/B frag offset
  const int hi = lane >> 5;

  // ---- resident weight fragments (8 Wk + 8 Wr = 64 VGPR)
  const f16* wkc = wkb + ((((size_t)z * 32 + wgi) * 2 + cp) * 32 + kq * 8) * 512;
  const f16* wrc = wrb + ((((size_t)z * 32 + wgi) * 2 + cp) * 32 + kq * 8) * 512;
  f16x8 wfk[8], wfr[8];
#pragma unroll
  for (int i = 0; i < 8; ++i) {
    wfk[i] = *(const f16x8*)(wkc + i * 512 + laneA);
    wfr[i] = *(const f16x8*)(wrc + i * 512 + laneA);
  }

  // gate-phase identity: thread = (batch b, col cj)
  const int cb = tid >> 4, cj = tid & 15;
  const float* bb = biasAll + (size_t)z * G_;
  float bias4[4];
#pragma unroll
  for (int g = 0; g < 4; ++g) bias4[g] = bb[g * H_ + j0 + cj];

  const unsigned char* mbytes = (const unsigned char*)maskp;
  const unsigned* mwords = (const unsigned*)maskp;
  const bool bytelay = (mbytes[1] != 0);

  float hstate = 0.f, cstate = 0.f;
  unsigned* flagd = flags + (size_t)dir * T_ * 32;
  const f32x16 vzero = {0.f};

  for (int s = 0; s < T_; ++s) {
    const int t = dir ? (T_ - 1 - s) : s;
    // ---- x-part: acc = x[t] @ Wk chunk (before the wait)
    const f16* xb = xh + (size_t)t * 16384 + (size_t)kq * 8 * 512 + laneA;
    f32x16 acc = vzero;
    {
      f16x8 xf[8];
#pragma unroll
      for (int i = 0; i < 8; ++i) xf[i] = *(const f16x8*)(xb + i * 512);
#pragma unroll
      for (int i = 0; i < 8; ++i)
        acc = __builtin_amdgcn_mfma_f32_32x32x16_f16(xf[i], wfk[i], acc, 0, 0, 0);
    }
    // gate-phase prefetches
    const size_t btm = (size_t)cb * T_ + t;
    const bool mv = bytelay ? (mbytes[btm] != 0) : (mwords[btm] != 0);
    float xr = 0.f;
    if (LAYER == 1 && dir == 0)
      xr = (float)res1h[(((size_t)t * 32 + wgi) * 32 + cb) * 16 + cj];

    // ---- wait for h[s-1]: wave0 agent-polls the 32 flag words (v4-proven)
    if (s > 0) {
      if (wave == 0) {
        const unsigned* fl = flagd + (size_t)(s - 1) * 32 + (lane & 31);
        while (true) {
          unsigned v = AL_U(fl);
          if (__ballot(v == 1u) == ~0ull) break;
        }
      }
      __syncthreads();
      const f16* hb;
      if (LAYER == 0) {
        const int tprev = dir ? (T_ - s) : (s - 1);
        hb = ring + ((size_t)dir * T_ + tprev) * 16384;
      } else {
        hb = ring + ((size_t)dir * 8 + ((s - 1) & 7)) * 16384;
      }
      hb += (size_t)kq * 8 * 512 + laneA;
      f16x8 hf[8];
#pragma unroll
      for (int i = 0; i < 8; ++i) hf[i] = *(const f16x8*)(hb + i * 512);
#pragma unroll
      for (int i = 0; i < 8; ++i)
        acc = __builtin_amdgcn_mfma_f32_32x32x16_f16(hf[i], wfr[i], acc, 0, 0, 0);
    }
    // ---- spill partials: row=(r&3)+8*(r>>2)+4*hi, col=lane&31 (2-way free)
#pragma unroll
    for (int r = 0; r < 16; ++r) {
      int row = (r & 3) + 8 * (r >> 2) + 4 * hi;
      zbuf[cp][kq][row][lane & 31] = acc[r];
    }
    __syncthreads();

    // ---- gates: sum 4 K-partials per gate (reads 2-way free)
    float zi = zbuf[0][0][cb][cj] + zbuf[0][1][cb][cj] + zbuf[0][2][cb][cj] + zbuf[0][3][cb][cj] + bias4[0];
    float zf = zbuf[0][0][cb][16 + cj] + zbuf[0][1][cb][16 + cj] + zbuf[0][2][cb][16 + cj] + zbuf[0][3][cb][16 + cj] + bias4[1];
    float zg = zbuf[1][0][cb][cj] + zbuf[1][1][cb][cj] + zbuf[1][2][cb][cj] + zbuf[1][3][cb][cj] + bias4[2];
    float zo = zbuf[1][0][cb][16 + cj] + zbuf[1][1][cb][16 + cj] + zbuf[1][2][cb][16 + cj] + zbuf[1][3][cb][16 + cj] + bias4[3];
    float ig = sigm(zi), fg = sigm(zf), gg = tanh_(zg), og = sigm(zo);
    float cn = fg * cstate + ig * gg;
    float hn = og * tanh_(cn);
    if (mv) { cstate = cn; hstate = hn; }  // masked steps carry h,c

    // ---- publish h (coalesced 1KB/WG): plain store -> shared XCD L2
    f16 h16 = (f16)hstate;
    unsigned short hu = __builtin_bit_cast(unsigned short, h16);
    unsigned ob = (unsigned)__shfl_xor((int)hu, 1);
    unsigned pk = (unsigned)hu | ((ob & 0xffffu) << 16);
    if ((cj & 1) == 0) {
      f16* pb;
      if (LAYER == 0) pb = ring + ((size_t)dir * T_ + t) * 16384;
      else            pb = ring + ((size_t)dir * 8 + (s & 7)) * 16384;
      *(unsigned*)(pb + (size_t)wgi * 512 + cb * 16 + cj) = pk;
    }
    // ---- release: drain publish to L2, then agent flag store (MALL)
    asm volatile("s_waitcnt vmcnt(0)" ::: "memory");
    __syncthreads();
    if (tid == 0) AS_U(&flagd[(size_t)s * 32 + wgi], 1u);

    // ---- layer-1 output (off critical path, after signal)
    if (LAYER == 1) {
      atomicAdd(&out[btm * H_ + j0 + cj], hstate + xr);
    }
  }
}

// ---------------------------------------------------------------- launch
extern "C" void kernel_launch(void* const* d_in, const int* in_sizes, int n_in,
                              void* d_out, int out_size, void* d_ws, size_t ws_size,
                              hipStream_t stream) {
  const float* x = (const float*)d_in[0];
  const void* maskp = (const void*)d_in[1];
  const float* Wk = (const float*)d_in[2];
  const float* Wr = (const float*)d_in[3];
  const float* bias = (const float*)d_in[4];
  float* out = (float*)d_out;
  (void)in_sizes; (void)n_in;

  // ---- workspace carve (51,382,272 B; same budget v4 passed with)
  char* ws = (char*)d_ws;
  f16* xh = (f16*)(ws);                              // 33,554,432 (reused as res1h)
  f16* wkb = (f16*)(ws + 33554432ull);               //  8,388,608 [4][32][2][32][512]
  f16* wrb = (f16*)(ws + 41943040ull);               //  8,388,608
  unsigned* flags0 = (unsigned*)(ws + 50331648ull);  //    262,144 [2][1024][32]
  unsigned* flags1 = (unsigned*)(ws + 50593792ull);  //    262,144
  Claim* cl0 = (Claim*)(ws + 50855936ull);           //      1,024
  Claim* cl1 = (Claim*)(ws + 50856960ull);           //      1,024
  f16* ring1 = (f16*)(ws + 50857984ull);             //    524,288 [2][8][16384]
  if (ws_size < 51382272ull) return;  // fail loudly (wrong output), don't fault

  // layer-0 ring = d_out scratch: [dir][t][16384] f16 = 64 MiB (hf|hb)
  f16* ring0 = (f16*)d_out;
  f16* hf = ring0;
  f16* hb = ring0 + (size_t)T_ * 16384;

  hipError_t e0 = hipMemsetAsync(flags0, 0, 526336ull, stream);  // flags+claims
  (void)e0;
  cvt_x_t<<<8192, 256, 0, stream>>>(x, xh);
  cvt_w<<<dim3(32, 4), 256, 0, stream>>>(Wk, wkb);
  cvt_w<<<dim3(32, 4), 256, 0, stream>>>(Wr, wrb);

  // layer 0
  lstm_rec6<0><<<512, 512, 0, stream>>>(xh, wkb, wrb, bias, maskp, ring0, flags0,
                                        cl0, (float*)nullptr, (const f16*)nullptr);
  sum_h<<<8192, 256, 0, stream>>>(hf, hb, xh);  // res1h overwrites xh

  // layer 1
  hipError_t e1 = hipMemsetAsync(d_out, 0, 67108864ull, stream);
  (void)e1;
  lstm_rec6<1><<<512, 512, 0, stream>>>(xh, wkb, wrb, bias, maskp, ring1, flags1,
                                        cl1, out, xh);
}

// Round 8
// 6942.753 us; speedup vs baseline: 1.0733x; 1.0733x over previous
//
#include <hip/hip_runtime.h>
#include <stdint.h>

// Encoder: 2-layer bidirectional masked LSTM. B=32 T=1024 D=H=512 G=4H=2048.
// v7 = v6 with the LDS pad made un-DCE-able (v6's `if (s_dir == -2)` guard was
// provably false -> compiler deleted the 33KB pad -> LDS 49.6KB -> up to 3
// role WGs stacked per CU sharing SIMDs -> 4.64ms rec. Fix: unconditional
// store + asm-consumed data-dependent read keeps the pad live; total LDS
// ~82.7KB > 80KB forces 1 WG/CU).
//  - 32x32x16 MFMA; Wk AND Wr register-resident (8+8 f16x8 = 64 regs/lane).
//  - conflict-free zbuf[2][4][32][48] (v6-verified: SQ_LDS_BANK_CONFLICT=0).
//  - h exchange: plain stores/loads through the direction's shared XCD L2.
//  - step flags: agent-scope atomics via MALL (v2/v3/v4/v6-proven).

#define B_ 32
#define T_ 1024
#define H_ 512
#define G_ 2048

typedef _Float16 f16;
typedef _Float16 f16x8 __attribute__((ext_vector_type(8)));
typedef float f32x16 __attribute__((ext_vector_type(16)));

#define AL_U(p) __hip_atomic_load((p), __ATOMIC_RELAXED, __HIP_MEMORY_SCOPE_AGENT)
#define AS_U(p, v) __hip_atomic_store((p), (v), __ATOMIC_RELAXED, __HIP_MEMORY_SCOPE_AGENT)
#define AADD_U(p, v) __hip_atomic_fetch_add((p), (v), __ATOMIC_RELAXED, __HIP_MEMORY_SCOPE_AGENT)

struct Claim {
  unsigned cnt[8];
  unsigned dirclaim;
  int xcddir[8];   // 0=undecided, 1/2=dir+1, -1=unused XCD
  unsigned pad[15];
};

__device__ __forceinline__ float sigm(float x) { return 1.f / (1.f + __expf(-x)); }
__device__ __forceinline__ float tanh_(float x) { return 1.f - 2.f / (__expf(2.f * x) + 1.f); }

// ---------------------------------------------------------------- converts
// x [b][t][512] f32 -> xh [t][ks32][b32][kk16] f16 (MFMA-A fragment-native)
__global__ void cvt_x_t(const float* __restrict__ x, f16* __restrict__ xh) {
  size_t j = (size_t)blockIdx.x * 256 + threadIdx.x;  // 2,097,152 threads
  int b = (int)(j >> 16);
  int t = (int)((j >> 6) & 1023);
  int d0 = (int)(j & 63) * 8;
  const float4* p = (const float4*)(x + ((size_t)b * T_ + t) * H_ + d0);
  float4 a = p[0], c = p[1];
  union { f16 h[8]; uint4 u; } r;
  r.h[0] = (f16)a.x; r.h[1] = (f16)a.y; r.h[2] = (f16)a.z; r.h[3] = (f16)a.w;
  r.h[4] = (f16)c.x; r.h[5] = (f16)c.y; r.h[6] = (f16)c.z; r.h[7] = (f16)c.w;
  size_t o = (((size_t)t * 32 + (d0 >> 4)) * 32 + b) * 16 + (d0 & 15);
  *(uint4*)(xh + o) = r.u;
}

// W [z4][k512][g2048] f32 -> wb [z4][wgi32][cp2][ks32][col32][kk16] f16
// where gate col = (2*cp + (col>>4))*512 + wgi*16 + (col&15), k = ks*16+kk.
__global__ void cvt_w(const float* __restrict__ W, f16* __restrict__ Wb) {
  const int wgi = blockIdx.x, z = blockIdx.y;
  const int tid = threadIdx.x;
  const float* src = W + (size_t)z * H_ * G_;
  __shared__ unsigned short st[512];
  for (int cp = 0; cp < 2; ++cp)
    for (int ks = 0; ks < 32; ++ks) {
      size_t cbase = ((((size_t)z * 32 + wgi) * 2 + cp) * 32 + ks) * 512;
#pragma unroll
      for (int pass = 0; pass < 2; ++pass) {
        int e = tid + pass * 256;
        int col = e & 31, kk = e >> 5;
        int gc = (2 * cp + (col >> 4)) * 512 + wgi * 16 + (col & 15);
        f16 v = (f16)src[(size_t)(ks * 16 + kk) * G_ + gc];
        st[col * 16 + kk] = __builtin_bit_cast(unsigned short, v);
      }
      __syncthreads();
      unsigned pk = (unsigned)st[2 * tid] | ((unsigned)st[2 * tid + 1] << 16);
      *((unsigned*)(Wb + cbase) + tid) = pk;
      __syncthreads();
    }
}

// res1h = hf + hb (elementwise; layouts identical)
__global__ void sum_h(const f16* __restrict__ a, const f16* __restrict__ b,
                      f16* __restrict__ r) {
  size_t i = ((size_t)blockIdx.x * 256 + threadIdx.x) * 8;
  f16x8 va = *(const f16x8*)(a + i), vb = *(const f16x8*)(b + i);
  *(f16x8*)(r + i) = va + vb;
}

// ---------------------------------------------------------------- recurrence
// Role WG: 512 thr, 8 waves: cp=wave&1 (coltile: gates i,f | g,o), kq=wave>>1
// (K-chunk of 128). All weights register-resident (8+8 f16x8 frags).
// LAYER0: ring = d_out scratch [dir][t][16384] (doubles as hf/hb output).
// LAYER1: ring = 8-slot; out[b][t][512] += h (+res1 for dir0) after signal.
template <int LAYER>
__global__ __launch_bounds__(512, 2) void lstm_rec7(
    const f16* __restrict__ xh,     // [t][ks][b][kk]
    const f16* __restrict__ wkb,    // [z][wgi][cp][ks][col][kk]
    const f16* __restrict__ wrb,
    const float* __restrict__ biasAll,  // [2][2][2048]
    const void* __restrict__ maskp,
    f16* __restrict__ ring,
    unsigned* __restrict__ flags,   // [2][1024][32] u32, pre-zeroed
    Claim* __restrict__ cl,         // pre-zeroed
    float* __restrict__ out,        // LAYER1 only
    const f16* __restrict__ res1h)  // LAYER1 only
{
  const int tid = threadIdx.x, wave = tid >> 6, lane = tid & 63;

  // ---- role claim (tid 0), broadcast via LDS (v3/v4-proven)
  __shared__ int s_dir, s_wgi;
  __shared__ float zbuf[2][4][32][48];   // 49,152 B, conflict-free strides
  __shared__ char lds_pad[33024];        // forces 1 WG/CU (total ~82.7KB)

  // Keep lds_pad live: unconditional store + asm-consumed dependent read
  // (v6's provably-false guard got DCE'd -> 3 WGs/CU -> regression).
  lds_pad[tid] = (char)tid;
  {
    char pv = ((volatile char*)lds_pad)[(tid * 37) & 32767];
    asm volatile("" :: "v"((int)pv));
  }

  if (tid == 0) {
    unsigned xcd;
    asm volatile("s_getreg_b32 %0, hwreg(HW_REG_XCC_ID)" : "=s"(xcd));
    xcd &= 7u;
    unsigned slot = AADD_U(&cl->cnt[xcd], 1u);
    int dir = -1, wgi = -1;
    if (slot < 32u) {
      if (slot == 31u) {
        unsigned d = AADD_U(&cl->dirclaim, 1u);
        int val = (d < 2u) ? (int)(d + 1u) : -1;
        __hip_atomic_store(&cl->xcddir[xcd], val, __ATOMIC_RELAXED, __HIP_MEMORY_SCOPE_AGENT);
      }
      while (true) {
        int v = __hip_atomic_load(&cl->xcddir[xcd], __ATOMIC_RELAXED, __HIP_MEMORY_SCOPE_AGENT);
        if (v != 0) { if (v > 0) { dir = v - 1; wgi = (int)slot; } break; }
        if (AL_U(&cl->dirclaim) >= 2u && AL_U(&cl->cnt[xcd]) < 32u) break;
        __builtin_amdgcn_s_sleep(2);
      }
    }
    s_dir = dir; s_wgi = wgi;
  }
  __syncthreads();
  const int dir = s_dir, wgi = s_wgi;
  if (dir < 0) return;

  const int cp = wave & 1, kq = wave >> 1;
  const int j0 = wgi * 16;
  const int z = LAYER * 2 + dir;
  const int laneA = (lane & 31) * 16 + (lane >> 5) * 8;  // A/B frag offset
  const int hi = lane >> 5;

  // ---- resident weight fragments (8 Wk + 8 Wr)
  const f16* wkc = wkb + ((((size_t)z * 32 + wgi) * 2 + cp) * 32 + kq * 8) * 512;
  const f16* wrc = wrb + ((((size_t)z * 32 + wgi) * 2 + cp) * 32 + kq * 8) * 512;
  f16x8 wfk[8], wfr[8];
#pragma unroll
  for (int i = 0; i < 8; ++i) {
    wfk[i] = *(const f16x8*)(wkc + i * 512 + laneA);
    wfr[i] = *(const f16x8*)(wrc + i * 512 + laneA);
  }

  // gate-phase identity: thread = (batch b, col cj)
  const int cb = tid >> 4, cj = tid & 15;
  const float* bb = biasAll + (size_t)z * G_;
  float bias4[4];
#pragma unroll
  for (int g = 0; g < 4; ++g) bias4[g] = bb[g * H_ + j0 + cj];

  const unsigned char* mbytes = (const unsigned char*)maskp;
  const unsigned* mwords = (const unsigned*)maskp;
  const bool bytelay = (mbytes[1] != 0);

  float hstate = 0.f, cstate = 0.f;
  unsigned* flagd = flags + (size_t)dir * T_ * 32;
  const f32x16 vzero = {0.f};

  for (int s = 0; s < T_; ++s) {
    const int t = dir ? (T_ - 1 - s) : s;
    // ---- x-part: acc = x[t] @ Wk chunk (before the wait)
    const f16* xb = xh + (size_t)t * 16384 + (size_t)kq * 8 * 512 + laneA;
    f32x16 acc = vzero;
    {
      f16x8 xf[8];
#pragma unroll
      for (int i = 0; i < 8; ++i) xf[i] = *(const f16x8*)(xb + i * 512);
#pragma unroll
      for (int i = 0; i < 8; ++i)
        acc = __builtin_amdgcn_mfma_f32_32x32x16_f16(xf[i], wfk[i], acc, 0, 0, 0);
    }
    // gate-phase prefetches
    const size_t btm = (size_t)cb * T_ + t;
    const bool mv = bytelay ? (mbytes[btm] != 0) : (mwords[btm] != 0);
    float xr = 0.f;
    if (LAYER == 1 && dir == 0)
      xr = (float)res1h[(((size_t)t * 32 + wgi) * 32 + cb) * 16 + cj];

    // ---- wait for h[s-1]: wave0 agent-polls the 32 flag words (v4-proven)
    if (s > 0) {
      if (wave == 0) {
        const unsigned* fl = flagd + (size_t)(s - 1) * 32 + (lane & 31);
        while (true) {
          unsigned v = AL_U(fl);
          if (__ballot(v == 1u) == ~0ull) break;
        }
      }
      __syncthreads();
      const f16* hb;
      if (LAYER == 0) {
        const int tprev = dir ? (T_ - s) : (s - 1);
        hb = ring + ((size_t)dir * T_ + tprev) * 16384;
      } else {
        hb = ring + ((size_t)dir * 8 + ((s - 1) & 7)) * 16384;
      }
      hb += (size_t)kq * 8 * 512 + laneA;
      f16x8 hf[8];
#pragma unroll
      for (int i = 0; i < 8; ++i) hf[i] = *(const f16x8*)(hb + i * 512);
#pragma unroll
      for (int i = 0; i < 8; ++i)
        acc = __builtin_amdgcn_mfma_f32_32x32x16_f16(hf[i], wfr[i], acc, 0, 0, 0);
    }
    // ---- spill partials: row=(r&3)+8*(r>>2)+4*hi, col=lane&31 (2-way free)
#pragma unroll
    for (int r = 0; r < 16; ++r) {
      int row = (r & 3) + 8 * (r >> 2) + 4 * hi;
      zbuf[cp][kq][row][lane & 31] = acc[r];
    }
    __syncthreads();

    // ---- gates: sum 4 K-partials per gate (reads 2-way free)
    float zi = zbuf[0][0][cb][cj] + zbuf[0][1][cb][cj] + zbuf[0][2][cb][cj] + zbuf[0][3][cb][cj] + bias4[0];
    float zf = zbuf[0][0][cb][16 + cj] + zbuf[0][1][cb][16 + cj] + zbuf[0][2][cb][16 + cj] + zbuf[0][3][cb][16 + cj] + bias4[1];
    float zg = zbuf[1][0][cb][cj] + zbuf[1][1][cb][cj] + zbuf[1][2][cb][cj] + zbuf[1][3][cb][cj] + bias4[2];
    float zo = zbuf[1][0][cb][16 + cj] + zbuf[1][1][cb][16 + cj] + zbuf[1][2][cb][16 + cj] + zbuf[1][3][cb][16 + cj] + bias4[3];
    float ig = sigm(zi), fg = sigm(zf), gg = tanh_(zg), og = sigm(zo);
    float cn = fg * cstate + ig * gg;
    float hn = og * tanh_(cn);
    if (mv) { cstate = cn; hstate = hn; }  // masked steps carry h,c

    // ---- publish h (coalesced 1KB/WG): plain store -> shared XCD L2
    f16 h16 = (f16)hstate;
    unsigned short hu = __builtin_bit_cast(unsigned short, h16);
    unsigned ob = (unsigned)__shfl_xor((int)hu, 1);
    unsigned pk = (unsigned)hu | ((ob & 0xffffu) << 16);
    if ((cj & 1) == 0) {
      f16* pb;
      if (LAYER == 0) pb = ring + ((size_t)dir * T_ + t) * 16384;
      else            pb = ring + ((size_t)dir * 8 + (s & 7)) * 16384;
      *(unsigned*)(pb + (size_t)wgi * 512 + cb * 16 + cj) = pk;
    }
    // ---- release: drain publish to L2, then agent flag store (MALL)
    asm volatile("s_waitcnt vmcnt(0)" ::: "memory");
    __syncthreads();
    if (tid == 0) AS_U(&flagd[(size_t)s * 32 + wgi], 1u);

    // ---- layer-1 output (off critical path, after signal)
    if (LAYER == 1) {
      atomicAdd(&out[btm * H_ + j0 + cj], hstate + xr);
    }
  }
}

// ---------------------------------------------------------------- launch
extern "C" void kernel_launch(void* const* d_in, const int* in_sizes, int n_in,
                              void* d_out, int out_size, void* d_ws, size_t ws_size,
                              hipStream_t stream) {
  const float* x = (const float*)d_in[0];
  const void* maskp = (const void*)d_in[1];
  const float* Wk = (const float*)d_in[2];
  const float* Wr = (const float*)d_in[3];
  const float* bias = (const float*)d_in[4];
  float* out = (float*)d_out;
  (void)in_sizes; (void)n_in;

  // ---- workspace carve (51,382,272 B; same budget v4/v6 passed with)
  char* ws = (char*)d_ws;
  f16* xh = (f16*)(ws);                              // 33,554,432 (reused as res1h)
  f16* wkb = (f16*)(ws + 33554432ull);               //  8,388,608 [4][32][2][32][512]
  f16* wrb = (f16*)(ws + 41943040ull);               //  8,388,608
  unsigned* flags0 = (unsigned*)(ws + 50331648ull);  //    262,144 [2][1024][32]
  unsigned* flags1 = (unsigned*)(ws + 50593792ull);  //    262,144
  Claim* cl0 = (Claim*)(ws + 50855936ull);           //      1,024
  Claim* cl1 = (Claim*)(ws + 50856960ull);           //      1,024
  f16* ring1 = (f16*)(ws + 50857984ull);             //    524,288 [2][8][16384]
  if (ws_size < 51382272ull) return;  // fail loudly (wrong output), don't fault

  // layer-0 ring = d_out scratch: [dir][t][16384] f16 = 64 MiB (hf|hb)
  f16* ring0 = (f16*)d_out;
  f16* hf = ring0;
  f16* hb = ring0 + (size_t)T_ * 16384;

  hipError_t e0 = hipMemsetAsync(flags0, 0, 526336ull, stream);  // flags+claims
  (void)e0;
  cvt_x_t<<<8192, 256, 0, stream>>>(x, xh);
  cvt_w<<<dim3(32, 4), 256, 0, stream>>>(Wk, wkb);
  cvt_w<<<dim3(32, 4), 256, 0, stream>>>(Wr, wrb);

  // layer 0
  lstm_rec7<0><<<512, 512, 0, stream>>>(xh, wkb, wrb, bias, maskp, ring0, flags0,
                                        cl0, (float*)nullptr, (const f16*)nullptr);
  sum_h<<<8192, 256, 0, stream>>>(hf, hb, xh);  // res1h overwrites xh

  // layer 1
  hipError_t e1 = hipMemsetAsync(d_out, 0, 67108864ull, stream);
  (void)e1;
  lstm_rec7<1><<<512, 512, 0, stream>>>(xh, wkb, wrb, bias, maskp, ring1, flags1,
                                        cl1, out, xh);
}

// Round 9
// 6375.047 us; speedup vs baseline: 1.1689x; 1.0891x over previous
//
#include <hip/hip_runtime.h>
#include <stdint.h>

// Encoder: 2-layer bidirectional masked LSTM. B=32 T=1024 D=H=512 G=4H=2048.
// v8 = v7 + two counter-diagnosed fixes:
//  (1) VGPR=88 proved wfk/wfr were REMATERIALIZED (reloaded from L2 every
//      step, ~8MB/step). Pin them with asm "+v" -> truly register-resident.
//  (2) rec0 (ring in d_out, fresh HBM lines) was 2.3x slower than rec1
//      (small L2 ring): publish drain paid HBM read-for-ownership each step
//      (FETCH_SIZE ~= 64MB d_out). Now BOTH layers publish to a 16-slot
//      L2-resident ring on the critical path; layer-0's full h history goes
//      to d_out via nontemporal stores AFTER the flag (off critical path).
// Compute core (v6/v7-verified): 32x32x16 MFMA, conflict-free zbuf, LDS pad
// (live) forces 1 WG/CU. Comm: XCD claim + MALL agent flags (v4-proven).

#define B_ 32
#define T_ 1024
#define H_ 512
#define G_ 2048

typedef _Float16 f16;
typedef _Float16 f16x8 __attribute__((ext_vector_type(8)));
typedef float f32x16 __attribute__((ext_vector_type(16)));

#define AL_U(p) __hip_atomic_load((p), __ATOMIC_RELAXED, __HIP_MEMORY_SCOPE_AGENT)
#define AS_U(p, v) __hip_atomic_store((p), (v), __ATOMIC_RELAXED, __HIP_MEMORY_SCOPE_AGENT)
#define AADD_U(p, v) __hip_atomic_fetch_add((p), (v), __ATOMIC_RELAXED, __HIP_MEMORY_SCOPE_AGENT)

struct Claim {
  unsigned cnt[8];
  unsigned dirclaim;
  int xcddir[8];   // 0=undecided, 1/2=dir+1, -1=unused XCD
  unsigned pad[15];
};

__device__ __forceinline__ float sigm(float x) { return 1.f / (1.f + __expf(-x)); }
__device__ __forceinline__ float tanh_(float x) { return 1.f - 2.f / (__expf(2.f * x) + 1.f); }

// ---------------------------------------------------------------- converts
// x [b][t][512] f32 -> xh [t][ks32][b32][kk16] f16 (MFMA-A fragment-native)
__global__ void cvt_x_t(const float* __restrict__ x, f16* __restrict__ xh) {
  size_t j = (size_t)blockIdx.x * 256 + threadIdx.x;  // 2,097,152 threads
  int b = (int)(j >> 16);
  int t = (int)((j >> 6) & 1023);
  int d0 = (int)(j & 63) * 8;
  const float4* p = (const float4*)(x + ((size_t)b * T_ + t) * H_ + d0);
  float4 a = p[0], c = p[1];
  union { f16 h[8]; uint4 u; } r;
  r.h[0] = (f16)a.x; r.h[1] = (f16)a.y; r.h[2] = (f16)a.z; r.h[3] = (f16)a.w;
  r.h[4] = (f16)c.x; r.h[5] = (f16)c.y; r.h[6] = (f16)c.z; r.h[7] = (f16)c.w;
  size_t o = (((size_t)t * 32 + (d0 >> 4)) * 32 + b) * 16 + (d0 & 15);
  *(uint4*)(xh + o) = r.u;
}

// W [z4][k512][g2048] f32 -> wb [z4][wgi32][cp2][ks32][col32][kk16] f16
// where gate col = (2*cp + (col>>4))*512 + wgi*16 + (col&15), k = ks*16+kk.
__global__ void cvt_w(const float* __restrict__ W, f16* __restrict__ Wb) {
  const int wgi = blockIdx.x, z = blockIdx.y;
  const int tid = threadIdx.x;
  const float* src = W + (size_t)z * H_ * G_;
  __shared__ unsigned short st[512];
  for (int cp = 0; cp < 2; ++cp)
    for (int ks = 0; ks < 32; ++ks) {
      size_t cbase = ((((size_t)z * 32 + wgi) * 2 + cp) * 32 + ks) * 512;
#pragma unroll
      for (int pass = 0; pass < 2; ++pass) {
        int e = tid + pass * 256;
        int col = e & 31, kk = e >> 5;
        int gc = (2 * cp + (col >> 4)) * 512 + wgi * 16 + (col & 15);
        f16 v = (f16)src[(size_t)(ks * 16 + kk) * G_ + gc];
        st[col * 16 + kk] = __builtin_bit_cast(unsigned short, v);
      }
      __syncthreads();
      unsigned pk = (unsigned)st[2 * tid] | ((unsigned)st[2 * tid + 1] << 16);
      *((unsigned*)(Wb + cbase) + tid) = pk;
      __syncthreads();
    }
}

// res1h = hf + hb (elementwise; layouts identical)
__global__ void sum_h(const f16* __restrict__ a, const f16* __restrict__ b,
                      f16* __restrict__ r) {
  size_t i = ((size_t)blockIdx.x * 256 + threadIdx.x) * 8;
  f16x8 va = *(const f16x8*)(a + i), vb = *(const f16x8*)(b + i);
  *(f16x8*)(r + i) = va + vb;
}

// ---------------------------------------------------------------- recurrence
// Role WG: 512 thr, 8 waves: cp=wave&1 (coltile: gates i,f | g,o), kq=wave>>1
// (K-chunk of 128). Weights register-resident (asm-pinned, 64 VGPR/lane).
// Both layers: publish ring = 16-slot [dir][16][16384] f16 (L2-resident).
// LAYER0 extra: h history -> d_out via nontemporal stores after the flag.
// LAYER1 extra: out[b][t][512] += h (+res1 for dir0) after the flag.
template <int LAYER>
__global__ __launch_bounds__(512, 2) void lstm_rec8(
    const f16* __restrict__ xh,     // [t][ks][b][kk]
    const f16* __restrict__ wkb,    // [z][wgi][cp][ks][col][kk]
    const f16* __restrict__ wrb,
    const float* __restrict__ biasAll,  // [2][2][2048]
    const void* __restrict__ maskp,
    f16* __restrict__ ring,         // [2][16][16384]
    unsigned* __restrict__ flags,   // [2][1024][32] u32, pre-zeroed
    Claim* __restrict__ cl,         // pre-zeroed
    f16* __restrict__ hout,         // LAYER0: [dir][t][16384] = d_out scratch
    float* __restrict__ out,        // LAYER1 only
    const f16* __restrict__ res1h)  // LAYER1 only
{
  const int tid = threadIdx.x, wave = tid >> 6, lane = tid & 63;

  // ---- role claim (tid 0), broadcast via LDS (v3/v4-proven)
  __shared__ int s_dir, s_wgi;
  __shared__ float zbuf[2][4][32][48];   // 49,152 B, conflict-free strides
  __shared__ char lds_pad[33024];        // forces 1 WG/CU (total ~82.7KB)

  // Keep lds_pad live (v7-proven pattern; v6's guard got DCE'd).
  lds_pad[tid] = (char)tid;
  {
    char pv = ((volatile char*)lds_pad)[(tid * 37) & 32767];
    asm volatile("" :: "v"((int)pv));
  }

  if (tid == 0) {
    unsigned xcd;
    asm volatile("s_getreg_b32 %0, hwreg(HW_REG_XCC_ID)" : "=s"(xcd));
    xcd &= 7u;
    unsigned slot = AADD_U(&cl->cnt[xcd], 1u);
    int dir = -1, wgi = -1;
    if (slot < 32u) {
      if (slot == 31u) {
        unsigned d = AADD_U(&cl->dirclaim, 1u);
        int val = (d < 2u) ? (int)(d + 1u) : -1;
        __hip_atomic_store(&cl->xcddir[xcd], val, __ATOMIC_RELAXED, __HIP_MEMORY_SCOPE_AGENT);
      }
      while (true) {
        int v = __hip_atomic_load(&cl->xcddir[xcd], __ATOMIC_RELAXED, __HIP_MEMORY_SCOPE_AGENT);
        if (v != 0) { if (v > 0) { dir = v - 1; wgi = (int)slot; } break; }
        if (AL_U(&cl->dirclaim) >= 2u && AL_U(&cl->cnt[xcd]) < 32u) break;
        __builtin_amdgcn_s_sleep(2);
      }
    }
    s_dir = dir; s_wgi = wgi;
  }
  __syncthreads();
  const int dir = s_dir, wgi = s_wgi;
  if (dir < 0) return;

  const int cp = wave & 1, kq = wave >> 1;
  const int j0 = wgi * 16;
  const int z = LAYER * 2 + dir;
  const int laneA = (lane & 31) * 16 + (lane >> 5) * 8;  // A/B frag offset
  const int hi = lane >> 5;

  // ---- resident weight fragments (8 Wk + 8 Wr = 64 VGPR), asm-pinned so
  // the compiler cannot rematerialize them as per-step global reloads
  // (v3..v7 all showed VGPR=88 <=> weights reloaded from L2 every step).
  const f16* wkc = wkb + ((((size_t)z * 32 + wgi) * 2 + cp) * 32 + kq * 8) * 512;
  const f16* wrc = wrb + ((((size_t)z * 32 + wgi) * 2 + cp) * 32 + kq * 8) * 512;
  f16x8 wfk[8], wfr[8];
#pragma unroll
  for (int i = 0; i < 8; ++i) {
    wfk[i] = *(const f16x8*)(wkc + i * 512 + laneA);
    wfr[i] = *(const f16x8*)(wrc + i * 512 + laneA);
  }
#pragma unroll
  for (int i = 0; i < 8; ++i) {
    asm volatile("" : "+v"(wfk[i]));
    asm volatile("" : "+v"(wfr[i]));
  }

  // gate-phase identity: thread = (batch b, col cj)
  const int cb = tid >> 4, cj = tid & 15;
  const float* bb = biasAll + (size_t)z * G_;
  float bias4[4];
#pragma unroll
  for (int g = 0; g < 4; ++g) bias4[g] = bb[g * H_ + j0 + cj];

  const unsigned char* mbytes = (const unsigned char*)maskp;
  const unsigned* mwords = (const unsigned*)maskp;
  const bool bytelay = (mbytes[1] != 0);

  float hstate = 0.f, cstate = 0.f;
  unsigned* flagd = flags + (size_t)dir * T_ * 32;
  const f32x16 vzero = {0.f};

  for (int s = 0; s < T_; ++s) {
    const int t = dir ? (T_ - 1 - s) : s;
    // ---- x-part: acc = x[t] @ Wk chunk (before the wait)
    const f16* xb = xh + (size_t)t * 16384 + (size_t)kq * 8 * 512 + laneA;
    f32x16 acc = vzero;
    {
      f16x8 xf[8];
#pragma unroll
      for (int i = 0; i < 8; ++i) xf[i] = *(const f16x8*)(xb + i * 512);
#pragma unroll
      for (int i = 0; i < 8; ++i)
        acc = __builtin_amdgcn_mfma_f32_32x32x16_f16(xf[i], wfk[i], acc, 0, 0, 0);
    }
    // gate-phase prefetches
    const size_t btm = (size_t)cb * T_ + t;
    const bool mv = bytelay ? (mbytes[btm] != 0) : (mwords[btm] != 0);
    float xr = 0.f;
    if (LAYER == 1 && dir == 0)
      xr = (float)res1h[(((size_t)t * 32 + wgi) * 32 + cb) * 16 + cj];

    // ---- wait for h[s-1]: wave0 agent-polls the 32 flag words (v4-proven)
    if (s > 0) {
      if (wave == 0) {
        const unsigned* fl = flagd + (size_t)(s - 1) * 32 + (lane & 31);
        while (true) {
          unsigned v = AL_U(fl);
          if (__ballot(v == 1u) == ~0ull) break;
        }
      }
      __syncthreads();
      const f16* hb = ring + ((size_t)dir * 16 + ((s - 1) & 15)) * 16384 +
                      (size_t)kq * 8 * 512 + laneA;
      f16x8 hf[8];
#pragma unroll
      for (int i = 0; i < 8; ++i) hf[i] = *(const f16x8*)(hb + i * 512);
#pragma unroll
      for (int i = 0; i < 8; ++i)
        acc = __builtin_amdgcn_mfma_f32_32x32x16_f16(hf[i], wfr[i], acc, 0, 0, 0);
    }
    // ---- spill partials: row=(r&3)+8*(r>>2)+4*hi, col=lane&31 (2-way free)
#pragma unroll
    for (int r = 0; r < 16; ++r) {
      int row = (r & 3) + 8 * (r >> 2) + 4 * hi;
      zbuf[cp][kq][row][lane & 31] = acc[r];
    }
    __syncthreads();

    // ---- gates: sum 4 K-partials per gate (reads 2-way free)
    float zi = zbuf[0][0][cb][cj] + zbuf[0][1][cb][cj] + zbuf[0][2][cb][cj] + zbuf[0][3][cb][cj] + bias4[0];
    float zf = zbuf[0][0][cb][16 + cj] + zbuf[0][1][cb][16 + cj] + zbuf[0][2][cb][16 + cj] + zbuf[0][3][cb][16 + cj] + bias4[1];
    float zg = zbuf[1][0][cb][cj] + zbuf[1][1][cb][cj] + zbuf[1][2][cb][cj] + zbuf[1][3][cb][cj] + bias4[2];
    float zo = zbuf[1][0][cb][16 + cj] + zbuf[1][1][cb][16 + cj] + zbuf[1][2][cb][16 + cj] + zbuf[1][3][cb][16 + cj] + bias4[3];
    float ig = sigm(zi), fg = sigm(zf), gg = tanh_(zg), og = sigm(zo);
    float cn = fg * cstate + ig * gg;
    float hn = og * tanh_(cn);
    if (mv) { cstate = cn; hstate = hn; }  // masked steps carry h,c

    // ---- publish h to the L2-resident ring slot (critical path)
    f16 h16 = (f16)hstate;
    unsigned short hu = __builtin_bit_cast(unsigned short, h16);
    unsigned ob = (unsigned)__shfl_xor((int)hu, 1);
    unsigned pk = (unsigned)hu | ((ob & 0xffffu) << 16);
    if ((cj & 1) == 0) {
      f16* pb = ring + ((size_t)dir * 16 + (s & 15)) * 16384;
      *(unsigned*)(pb + (size_t)wgi * 512 + cb * 16 + cj) = pk;
    }
    // ---- release: drain ring publish (L2 hit, fast), then agent flag store
    asm volatile("s_waitcnt vmcnt(0)" ::: "memory");
    __syncthreads();
    if (tid == 0) AS_U(&flagd[(size_t)s * 32 + wgi], 1u);

    // ---- off-critical-path outputs (after the flag)
    if (LAYER == 0) {
      if ((cj & 1) == 0) {
        f16* hx = hout + ((size_t)dir * T_ + t) * 16384;
        __builtin_nontemporal_store(pk, (unsigned*)(hx + (size_t)wgi * 512 + cb * 16 + cj));
      }
    } else {
      atomicAdd(&out[btm * H_ + j0 + cj], hstate + xr);
    }
  }
}

// ---------------------------------------------------------------- launch
extern "C" void kernel_launch(void* const* d_in, const int* in_sizes, int n_in,
                              void* d_out, int out_size, void* d_ws, size_t ws_size,
                              hipStream_t stream) {
  const float* x = (const float*)d_in[0];
  const void* maskp = (const void*)d_in[1];
  const float* Wk = (const float*)d_in[2];
  const float* Wr = (const float*)d_in[3];
  const float* bias = (const float*)d_in[4];
  float* out = (float*)d_out;
  (void)in_sizes; (void)n_in;

  // ---- workspace carve (51,906,560 B)
  char* ws = (char*)d_ws;
  f16* xh = (f16*)(ws);                              // 33,554,432 (reused as res1h)
  f16* wkb = (f16*)(ws + 33554432ull);               //  8,388,608 [4][32][2][32][512]
  f16* wrb = (f16*)(ws + 41943040ull);               //  8,388,608
  unsigned* flags0 = (unsigned*)(ws + 50331648ull);  //    262,144 [2][1024][32]
  unsigned* flags1 = (unsigned*)(ws + 50593792ull);  //    262,144
  Claim* cl0 = (Claim*)(ws + 50855936ull);           //      1,024
  Claim* cl1 = (Claim*)(ws + 50856960ull);           //      1,024
  f16* ring = (f16*)(ws + 50857984ull);              //  1,048,576 [2][16][16384]
  if (ws_size < 51906560ull) return;  // fail loudly (wrong output), don't fault

  // layer-0 h history: d_out scratch [dir][t][16384] f16 = 64 MiB (hf|hb)
  f16* hf = (f16*)d_out;
  f16* hb = (f16*)d_out + (size_t)T_ * 16384;

  hipError_t e0 = hipMemsetAsync(flags0, 0, 526336ull, stream);  // flags+claims
  (void)e0;
  cvt_x_t<<<8192, 256, 0, stream>>>(x, xh);
  cvt_w<<<dim3(32, 4), 256, 0, stream>>>(Wk, wkb);
  cvt_w<<<dim3(32, 4), 256, 0, stream>>>(Wr, wrb);

  // layer 0
  lstm_rec8<0><<<512, 512, 0, stream>>>(xh, wkb, wrb, bias, maskp, ring, flags0,
                                        cl0, hf, (float*)nullptr, (const f16*)nullptr);
  sum_h<<<8192, 256, 0, stream>>>(hf, hb, xh);  // res1h overwrites xh

  // layer 1
  hipError_t e1 = hipMemsetAsync(d_out, 0, 67108864ull, stream);
  (void)e1;
  lstm_rec8<1><<<512, 512, 0, stream>>>(xh, wkb, wrb, bias, maskp, ring, flags1,
                                        cl1, (f16*)nullptr, out, xh);
}

// Round 11
// 6364.647 us; speedup vs baseline: 1.1708x; 1.0016x over previous
//
#include <hip/hip_runtime.h>
#include <stdint.h>

// Encoder: 2-layer bidirectional masked LSTM. B=32 T=1024 D=H=512 G=4H=2048.
// v10 = v8 (last correct version) + ONE change: amdgpu_waves_per_eu(2,2).
//  Diagnosis chain: VGPR_Count=88 across v3..v9 = regalloc targeting default
//  ~4-5 waves/SIMD occupancy (launch_bounds' 2nd arg is only a MIN-waves
//  bound, not a target), so the 128 weight regs were remat'ed/spilled into
//  ~4MB/step/dir of L2 reloads — the measured XCD-L2-BW bound. The LDS pad
//  already caps us at 1 WG/CU (2 waves/EU), so pinning waves_per_eu=(2,2)
//  unlocks the 256-reg budget and keeps weights genuinely register-resident.
//  (v9's inline-asm MFMA broke numerics: hazard recognizer can't insert the
//  required MFMA->VALU wait states through INLINEASM — reverted to intrinsics.)
// Core (v6..v8-verified): 32x32x16 MFMA, conflict-free zbuf (bank conflicts=0),
// live LDS pad, XCD claim, MALL agent flags, 16-slot L2 ring, nt-store h
// history / atomicAdd outputs after the flag.

#define B_ 32
#define T_ 1024
#define H_ 512
#define G_ 2048

typedef _Float16 f16;
typedef _Float16 f16x8 __attribute__((ext_vector_type(8)));
typedef float f32x16 __attribute__((ext_vector_type(16)));

#define AL_U(p) __hip_atomic_load((p), __ATOMIC_RELAXED, __HIP_MEMORY_SCOPE_AGENT)
#define AS_U(p, v) __hip_atomic_store((p), (v), __ATOMIC_RELAXED, __HIP_MEMORY_SCOPE_AGENT)
#define AADD_U(p, v) __hip_atomic_fetch_add((p), (v), __ATOMIC_RELAXED, __HIP_MEMORY_SCOPE_AGENT)

struct Claim {
  unsigned cnt[8];
  unsigned dirclaim;
  int xcddir[8];   // 0=undecided, 1/2=dir+1, -1=unused XCD
  unsigned pad[15];
};

__device__ __forceinline__ float sigm(float x) { return 1.f / (1.f + __expf(-x)); }
__device__ __forceinline__ float tanh_(float x) { return 1.f - 2.f / (__expf(2.f * x) + 1.f); }

// ---------------------------------------------------------------- converts
// x [b][t][512] f32 -> xh [t][ks32][b32][kk16] f16 (MFMA-A fragment-native)
__global__ void cvt_x_t(const float* __restrict__ x, f16* __restrict__ xh) {
  size_t j = (size_t)blockIdx.x * 256 + threadIdx.x;  // 2,097,152 threads
  int b = (int)(j >> 16);
  int t = (int)((j >> 6) & 1023);
  int d0 = (int)(j & 63) * 8;
  const float4* p = (const float4*)(x + ((size_t)b * T_ + t) * H_ + d0);
  float4 a = p[0], c = p[1];
  union { f16 h[8]; uint4 u; } r;
  r.h[0] = (f16)a.x; r.h[1] = (f16)a.y; r.h[2] = (f16)a.z; r.h[3] = (f16)a.w;
  r.h[4] = (f16)c.x; r.h[5] = (f16)c.y; r.h[6] = (f16)c.z; r.h[7] = (f16)c.w;
  size_t o = (((size_t)t * 32 + (d0 >> 4)) * 32 + b) * 16 + (d0 & 15);
  *(uint4*)(xh + o) = r.u;
}

// W [z4][k512][g2048] f32 -> wb [z4][wgi32][cp2][ks32][col32][kk16] f16
// where gate col = (2*cp + (col>>4))*512 + wgi*16 + (col&15), k = ks*16+kk.
__global__ void cvt_w(const float* __restrict__ W, f16* __restrict__ Wb) {
  const int wgi = blockIdx.x, z = blockIdx.y;
  const int tid = threadIdx.x;
  const float* src = W + (size_t)z * H_ * G_;
  __shared__ unsigned short st[512];
  for (int cp = 0; cp < 2; ++cp)
    for (int ks = 0; ks < 32; ++ks) {
      size_t cbase = ((((size_t)z * 32 + wgi) * 2 + cp) * 32 + ks) * 512;
#pragma unroll
      for (int pass = 0; pass < 2; ++pass) {
        int e = tid + pass * 256;
        int col = e & 31, kk = e >> 5;
        int gc = (2 * cp + (col >> 4)) * 512 + wgi * 16 + (col & 15);
        f16 v = (f16)src[(size_t)(ks * 16 + kk) * G_ + gc];
        st[col * 16 + kk] = __builtin_bit_cast(unsigned short, v);
      }
      __syncthreads();
      unsigned pk = (unsigned)st[2 * tid] | ((unsigned)st[2 * tid + 1] << 16);
      *((unsigned*)(Wb + cbase) + tid) = pk;
      __syncthreads();
    }
}

// res1h = hf + hb (elementwise; layouts identical)
__global__ void sum_h(const f16* __restrict__ a, const f16* __restrict__ b,
                      f16* __restrict__ r) {
  size_t i = ((size_t)blockIdx.x * 256 + threadIdx.x) * 8;
  f16x8 va = *(const f16x8*)(a + i), vb = *(const f16x8*)(b + i);
  *(f16x8*)(r + i) = va + vb;
}

// ---------------------------------------------------------------- recurrence
// Role WG: 512 thr, 8 waves: cp=wave&1 (coltile: gates i,f | g,o), kq=wave>>1
// (K-chunk of 128). Weights register-resident (waves_per_eu(2,2) => 256-reg
// budget; asm "+v" pins block remat). 16-slot L2-resident publish ring.
template <int LAYER>
__global__ __attribute__((amdgpu_flat_work_group_size(512, 512),
                          amdgpu_waves_per_eu(2, 2)))
void lstm_rec10(
    const f16* __restrict__ xh,     // [t][ks][b][kk]
    const f16* __restrict__ wkb,    // [z][wgi][cp][ks][col][kk]
    const f16* __restrict__ wrb,
    const float* __restrict__ biasAll,  // [2][2][2048]
    const void* __restrict__ maskp,
    f16* __restrict__ ring,         // [2][16][16384]
    unsigned* __restrict__ flags,   // [2][1024][32] u32, pre-zeroed
    Claim* __restrict__ cl,         // pre-zeroed
    f16* __restrict__ hout,         // LAYER0: [dir][t][16384] = d_out scratch
    float* __restrict__ out,        // LAYER1 only
    const f16* __restrict__ res1h)  // LAYER1 only
{
  const int tid = threadIdx.x, wave = tid >> 6, lane = tid & 63;

  // ---- role claim (tid 0), broadcast via LDS (v3/v4-proven)
  __shared__ int s_dir, s_wgi;
  __shared__ float zbuf[2][4][32][48];   // 49,152 B, conflict-free strides
  __shared__ char lds_pad[33024];        // forces 1 WG/CU (total ~82.7KB)

  // Keep lds_pad live (v7-proven pattern; v6's guard got DCE'd).
  lds_pad[tid] = (char)tid;
  {
    char pv = ((volatile char*)lds_pad)[(tid * 37) & 32767];
    asm volatile("" :: "v"((int)pv));
  }

  if (tid == 0) {
    unsigned xcd;
    asm volatile("s_getreg_b32 %0, hwreg(HW_REG_XCC_ID)" : "=s"(xcd));
    xcd &= 7u;
    unsigned slot = AADD_U(&cl->cnt[xcd], 1u);
    int dir = -1, wgi = -1;
    if (slot < 32u) {
      if (slot == 31u) {
        unsigned d = AADD_U(&cl->dirclaim, 1u);
        int val = (d < 2u) ? (int)(d + 1u) : -1;
        __hip_atomic_store(&cl->xcddir[xcd], val, __ATOMIC_RELAXED, __HIP_MEMORY_SCOPE_AGENT);
      }
      while (true) {
        int v = __hip_atomic_load(&cl->xcddir[xcd], __ATOMIC_RELAXED, __HIP_MEMORY_SCOPE_AGENT);
        if (v != 0) { if (v > 0) { dir = v - 1; wgi = (int)slot; } break; }
        if (AL_U(&cl->dirclaim) >= 2u && AL_U(&cl->cnt[xcd]) < 32u) break;
        __builtin_amdgcn_s_sleep(2);
      }
    }
    s_dir = dir; s_wgi = wgi;
  }
  __syncthreads();
  const int dir = s_dir, wgi = s_wgi;
  if (dir < 0) return;

  const int cp = wave & 1, kq = wave >> 1;
  const int j0 = wgi * 16;
  const int z = LAYER * 2 + dir;
  const int laneA = (lane & 31) * 16 + (lane >> 5) * 8;  // A/B frag offset
  const int hi = lane >> 5;

  // ---- resident weight fragments (8 Wk + 8 Wr = 64 VGPR), pinned
  const f16* wkc = wkb + ((((size_t)z * 32 + wgi) * 2 + cp) * 32 + kq * 8) * 512;
  const f16* wrc = wrb + ((((size_t)z * 32 + wgi) * 2 + cp) * 32 + kq * 8) * 512;
  f16x8 wfk[8], wfr[8];
#pragma unroll
  for (int i = 0; i < 8; ++i) {
    wfk[i] = *(const f16x8*)(wkc + i * 512 + laneA);
    wfr[i] = *(const f16x8*)(wrc + i * 512 + laneA);
  }
#pragma unroll
  for (int i = 0; i < 8; ++i) {
    asm volatile("" : "+v"(wfk[i]));
    asm volatile("" : "+v"(wfr[i]));
  }

  // gate-phase identity: thread = (batch b, col cj)
  const int cb = tid >> 4, cj = tid & 15;
  const float* bb = biasAll + (size_t)z * G_;
  float bias4[4];
#pragma unroll
  for (int g = 0; g < 4; ++g) bias4[g] = bb[g * H_ + j0 + cj];

  const unsigned char* mbytes = (const unsigned char*)maskp;
  const unsigned* mwords = (const unsigned*)maskp;
  const bool bytelay = (mbytes[1] != 0);

  float hstate = 0.f, cstate = 0.f;
  unsigned* flagd = flags + (size_t)dir * T_ * 32;
  const f32x16 vzero = {0.f};

  for (int s = 0; s < T_; ++s) {
    const int t = dir ? (T_ - 1 - s) : s;
    // ---- x-part: acc = x[t] @ Wk chunk (before the wait)
    const f16* xb = xh + (size_t)t * 16384 + (size_t)kq * 8 * 512 + laneA;
    f32x16 acc = vzero;
    {
      f16x8 xf[8];
#pragma unroll
      for (int i = 0; i < 8; ++i) xf[i] = *(const f16x8*)(xb + i * 512);
#pragma unroll
      for (int i = 0; i < 8; ++i)
        acc = __builtin_amdgcn_mfma_f32_32x32x16_f16(xf[i], wfk[i], acc, 0, 0, 0);
    }
    // gate-phase prefetches
    const size_t btm = (size_t)cb * T_ + t;
    const bool mv = bytelay ? (mbytes[btm] != 0) : (mwords[btm] != 0);
    float xr = 0.f;
    if (LAYER == 1 && dir == 0)
      xr = (float)res1h[(((size_t)t * 32 + wgi) * 32 + cb) * 16 + cj];

    // ---- wait for h[s-1]: wave0 agent-polls the 32 flag words (v4-proven)
    if (s > 0) {
      if (wave == 0) {
        const unsigned* fl = flagd + (size_t)(s - 1) * 32 + (lane & 31);
        while (true) {
          unsigned v = AL_U(fl);
          if (__ballot(v == 1u) == ~0ull) break;
        }
      }
      __syncthreads();
      const f16* hb = ring + ((size_t)dir * 16 + ((s - 1) & 15)) * 16384 +
                      (size_t)kq * 8 * 512 + laneA;
      f16x8 hf[8];
#pragma unroll
      for (int i = 0; i < 8; ++i) hf[i] = *(const f16x8*)(hb + i * 512);
#pragma unroll
      for (int i = 0; i < 8; ++i)
        acc = __builtin_amdgcn_mfma_f32_32x32x16_f16(hf[i], wfr[i], acc, 0, 0, 0);
    }
    // ---- spill partials: row=(r&3)+8*(r>>2)+4*hi, col=lane&31 (2-way free)
#pragma unroll
    for (int r = 0; r < 16; ++r) {
      int row = (r & 3) + 8 * (r >> 2) + 4 * hi;
      zbuf[cp][kq][row][lane & 31] = acc[r];
    }
    __syncthreads();

    // ---- gates: sum 4 K-partials per gate (reads 2-way free)
    float zi = zbuf[0][0][cb][cj] + zbuf[0][1][cb][cj] + zbuf[0][2][cb][cj] + zbuf[0][3][cb][cj] + bias4[0];
    float zf = zbuf[0][0][cb][16 + cj] + zbuf[0][1][cb][16 + cj] + zbuf[0][2][cb][16 + cj] + zbuf[0][3][cb][16 + cj] + bias4[1];
    float zg = zbuf[1][0][cb][cj] + zbuf[1][1][cb][cj] + zbuf[1][2][cb][cj] + zbuf[1][3][cb][cj] + bias4[2];
    float zo = zbuf[1][0][cb][16 + cj] + zbuf[1][1][cb][16 + cj] + zbuf[1][2][cb][16 + cj] + zbuf[1][3][cb][16 + cj] + bias4[3];
    float ig = sigm(zi), fg = sigm(zf), gg = tanh_(zg), og = sigm(zo);
    float cn = fg * cstate + ig * gg;
    float hn = og * tanh_(cn);
    if (mv) { cstate = cn; hstate = hn; }  // masked steps carry h,c

    // ---- publish h to the L2-resident ring slot (critical path)
    f16 h16 = (f16)hstate;
    unsigned short hu = __builtin_bit_cast(unsigned short, h16);
    unsigned ob = (unsigned)__shfl_xor((int)hu, 1);
    unsigned pk = (unsigned)hu | ((ob & 0xffffu) << 16);
    if ((cj & 1) == 0) {
      f16* pb = ring + ((size_t)dir * 16 + (s & 15)) * 16384;
      *(unsigned*)(pb + (size_t)wgi * 512 + cb * 16 + cj) = pk;
    }
    // ---- release: drain ring publish (L2 hit, fast), then agent flag store
    asm volatile("s_waitcnt vmcnt(0)" ::: "memory");
    __syncthreads();
    if (tid == 0) AS_U(&flagd[(size_t)s * 32 + wgi], 1u);

    // ---- off-critical-path outputs (after the flag)
    if (LAYER == 0) {
      if ((cj & 1) == 0) {
        f16* hx = hout + ((size_t)dir * T_ + t) * 16384;
        __builtin_nontemporal_store(pk, (unsigned*)(hx + (size_t)wgi * 512 + cb * 16 + cj));
      }
    } else {
      atomicAdd(&out[btm * H_ + j0 + cj], hstate + xr);
    }
  }
}

// ---------------------------------------------------------------- launch
extern "C" void kernel_launch(void* const* d_in, const int* in_sizes, int n_in,
                              void* d_out, int out_size, void* d_ws, size_t ws_size,
                              hipStream_t stream) {
  const float* x = (const float*)d_in[0];
  const void* maskp = (const void*)d_in[1];
  const float* Wk = (const float*)d_in[2];
  const float* Wr = (const float*)d_in[3];
  const float* bias = (const float*)d_in[4];
  float* out = (float*)d_out;
  (void)in_sizes; (void)n_in;

  // ---- workspace carve (51,906,560 B; v8-proven budget)
  char* ws = (char*)d_ws;
  f16* xh = (f16*)(ws);                              // 33,554,432 (reused as res1h)
  f16* wkb = (f16*)(ws + 33554432ull);               //  8,388,608 [4][32][2][32][512]
  f16* wrb = (f16*)(ws + 41943040ull);               //  8,388,608
  unsigned* flags0 = (unsigned*)(ws + 50331648ull);  //    262,144 [2][1024][32]
  unsigned* flags1 = (unsigned*)(ws + 50593792ull);  //    262,144
  Claim* cl0 = (Claim*)(ws + 50855936ull);           //      1,024
  Claim* cl1 = (Claim*)(ws + 50856960ull);           //      1,024
  f16* ring = (f16*)(ws + 50857984ull);              //  1,048,576 [2][16][16384]
  if (ws_size < 51906560ull) return;  // fail loudly (wrong output), don't fault

  // layer-0 h history: d_out scratch [dir][t][16384] f16 = 64 MiB (hf|hb)
  f16* hf = (f16*)d_out;
  f16* hb = (f16*)d_out + (size_t)T_ * 16384;

  hipError_t e0 = hipMemsetAsync(flags0, 0, 526336ull, stream);  // flags+claims
  (void)e0;
  cvt_x_t<<<8192, 256, 0, stream>>>(x, xh);
  cvt_w<<<dim3(32, 4), 256, 0, stream>>>(Wk, wkb);
  cvt_w<<<dim3(32, 4), 256, 0, stream>>>(Wr, wrb);

  // layer 0
  lstm_rec10<0><<<512, 512, 0, stream>>>(xh, wkb, wrb, bias, maskp, ring, flags0,
                                         cl0, hf, (float*)nullptr, (const f16*)nullptr);
  sum_h<<<8192, 256, 0, stream>>>(hf, hb, xh);  // res1h overwrites xh

  // layer 1
  hipError_t e1 = hipMemsetAsync(d_out, 0, 67108864ull, stream);
  (void)e1;
  lstm_rec10<1><<<512, 512, 0, stream>>>(xh, wkb, wrb, bias, maskp, ring, flags1,
                                         cl1, (f16*)nullptr, out, xh);
}